// Round 1
// baseline (821.647 us; speedup 1.0000x reference)
//
#include <hip/hip_runtime.h>

#define HIDDEN 64
#define NREL 50
#define NPAIR (NREL * NREL)

// ---------------------------------------------------------------------------
// Kernel 1: precompute tables.
//   M2[p][j] = sum_k relu( sum_i pair_p[i] * W_msg[i][k] ) * W_upd[64+k][j]
//     where p = ra*50+rb, pair_p = concat(rel_emb[ra], rel_emb[rb])  [2500x64]
//   Hc[r][j] = sum_i rel_emb[r][i] * W_upd[i][j]                      [50x64]
// One block (64 threads) per p. ~41 MFLOP total: trivial.
// ---------------------------------------------------------------------------
__global__ void precompute_tables(const float* __restrict__ rel_emb,
                                  const float* __restrict__ W_msg,
                                  const float* __restrict__ W_upd,
                                  float* __restrict__ M2,
                                  float* __restrict__ Hc) {
    const int p = blockIdx.x;      // 0..2499
    const int j = threadIdx.x;     // 0..63
    const int ra = p / NREL, rb = p % NREL;

    __shared__ float msg[HIDDEN];

    const float* ha = rel_emb + ra * HIDDEN;
    const float* hb = rel_emb + rb * HIDDEN;

    // thread j computes msg[j] (column j of W_msg; lane-coalesced reads)
    float acc = 0.f;
    #pragma unroll 8
    for (int i = 0; i < HIDDEN; ++i) acc += ha[i] * W_msg[i * HIDDEN + j];
    #pragma unroll 8
    for (int i = 0; i < HIDDEN; ++i) acc += hb[i] * W_msg[(HIDDEN + i) * HIDDEN + j];
    msg[j] = fmaxf(acc, 0.f);
    __syncthreads();

    float acc2 = 0.f;
    #pragma unroll 8
    for (int k = 0; k < HIDDEN; ++k) acc2 += msg[k] * W_upd[(HIDDEN + k) * HIDDEN + j];
    M2[p * HIDDEN + j] = acc2;

    if (p < NREL) {  // first 50 blocks also fill Hc
        float acc3 = 0.f;
        #pragma unroll 8
        for (int i = 0; i < HIDDEN; ++i) acc3 += rel_emb[p * HIDDEN + i] * W_upd[i * HIDDEN + j];
        Hc[p * HIDDEN + j] = acc3;
    }
}

// ---------------------------------------------------------------------------
// Kernel 2: scatter. One wave per triangle iteration; lane d handles dim d.
//   out[edge_ac[t]][d] += M2[ rel[edge_ab[t]]*50 + rel[edge_bc[t]] ][d]
// Index loads are wave-uniform (one transaction); M2 row is L2-hot (640 KB);
// the 64-lane atomicAdd covers 4 contiguous 64B lines of the out row.
// ---------------------------------------------------------------------------
__global__ void scatter_tri(const int* __restrict__ rel,
                            const int* __restrict__ edge_ab,
                            const int* __restrict__ edge_bc,
                            const int* __restrict__ edge_ac,
                            const float* __restrict__ M2,
                            float* __restrict__ out,
                            int num_tri) {
    const int lane   = threadIdx.x & 63;
    const int wave   = (int)((blockIdx.x * blockDim.x + threadIdx.x) >> 6);
    const int nwaves = (int)((gridDim.x * blockDim.x) >> 6);

    for (int t = wave; t < num_tri; t += nwaves) {
        const int ab = edge_ab[t];
        const int bc = edge_bc[t];
        const int ac = edge_ac[t];
        const int p  = rel[ab] * NREL + rel[bc];
        const float v = M2[p * HIDDEN + lane];
        unsafeAtomicAdd(&out[(size_t)ac * HIDDEN + lane], v);
    }
}

// ---------------------------------------------------------------------------
// Kernel 3: finalize. out[e][d] = relu(out[e][d] + Hc[rel[e]][d]), float4.
// ---------------------------------------------------------------------------
__global__ void finalize(const int* __restrict__ rel,
                         const float* __restrict__ Hc,
                         float* __restrict__ out,
                         int num_edge) {
    const int total = num_edge * (HIDDEN / 4);  // float4 elements
    int i = blockIdx.x * blockDim.x + threadIdx.x;
    const int stride = gridDim.x * blockDim.x;
    for (; i < total; i += stride) {
        const int e = i >> 4;          // 16 float4 per edge row
        const int q = i & 15;
        const int r = rel[e];
        float4 a = ((const float4*)out)[i];
        float4 h = ((const float4*)(Hc + r * HIDDEN))[q];
        float4 o;
        o.x = fmaxf(a.x + h.x, 0.f);
        o.y = fmaxf(a.y + h.y, 0.f);
        o.z = fmaxf(a.z + h.z, 0.f);
        o.w = fmaxf(a.w + h.w, 0.f);
        ((float4*)out)[i] = o;
    }
}

extern "C" void kernel_launch(void* const* d_in, const int* in_sizes, int n_in,
                              void* d_out, int out_size, void* d_ws, size_t ws_size,
                              hipStream_t stream) {
    const float* rel_emb = (const float*)d_in[0];   // [50,64]
    const float* W_msg   = (const float*)d_in[1];   // [128,64]
    const float* W_upd   = (const float*)d_in[2];   // [128,64]
    // d_in[3]=src, d_in[4]=dst are unused by the reference.
    const int* rel     = (const int*)d_in[5];       // [E]
    const int* edge_ab = (const int*)d_in[6];       // [T]
    const int* edge_bc = (const int*)d_in[7];       // [T]
    const int* edge_ac = (const int*)d_in[8];       // [T]
    float* out = (float*)d_out;                     // [E,64]

    const int num_edge = in_sizes[5];
    const int num_tri  = in_sizes[6];

    float* M2 = (float*)d_ws;                 // 2500*64*4 = 640 KB
    float* Hc = M2 + NPAIR * HIDDEN;          // 50*64*4  = 12.8 KB

    // out is poisoned 0xAA before every timed launch: zero it (async, capturable).
    hipMemsetAsync(d_out, 0, (size_t)out_size * sizeof(float), stream);

    precompute_tables<<<NPAIR, HIDDEN, 0, stream>>>(rel_emb, W_msg, W_upd, M2, Hc);

    // 8192 blocks x 4 waves = 32768 waves, ~61 triangles each (grid-stride).
    scatter_tri<<<8192, 256, 0, stream>>>(rel, edge_ab, edge_bc, edge_ac, M2, out, num_tri);

    const int total4 = num_edge * (HIDDEN / 4);
    int fin_blocks = (total4 + 255) / 256;
    if (fin_blocks > 65535 * 8) fin_blocks = 65535 * 8;
    finalize<<<fin_blocks, 256, 0, stream>>>(rel, Hc, out, num_edge);
}

// Round 2
// 574.292 us; speedup vs baseline: 1.4307x; 1.4307x over previous
//
#include <hip/hip_runtime.h>

#define HIDDEN 64
#define NREL 50
#define NPAIR (NREL * NREL)
#define TILE 4096           // scan tile: 256 threads x 16 elements

// ---------------------------------------------------------------------------
// Kernel 1: precompute tables.
//   M2[p][j] = sum_k relu( sum_i pair_p[i] * W_msg[i][k] ) * W_upd[64+k][j]
//   Hc[r][j] = sum_i rel_emb[r][i] * W_upd[i][j]
// ---------------------------------------------------------------------------
__global__ void precompute_tables(const float* __restrict__ rel_emb,
                                  const float* __restrict__ W_msg,
                                  const float* __restrict__ W_upd,
                                  float* __restrict__ M2,
                                  float* __restrict__ Hc) {
    const int p = blockIdx.x;      // 0..2499
    const int j = threadIdx.x;     // 0..63
    const int ra = p / NREL, rb = p % NREL;

    __shared__ float msg[HIDDEN];

    const float* ha = rel_emb + ra * HIDDEN;
    const float* hb = rel_emb + rb * HIDDEN;

    float acc = 0.f;
    #pragma unroll 8
    for (int i = 0; i < HIDDEN; ++i) acc += ha[i] * W_msg[i * HIDDEN + j];
    #pragma unroll 8
    for (int i = 0; i < HIDDEN; ++i) acc += hb[i] * W_msg[(HIDDEN + i) * HIDDEN + j];
    msg[j] = fmaxf(acc, 0.f);
    __syncthreads();

    float acc2 = 0.f;
    #pragma unroll 8
    for (int k = 0; k < HIDDEN; ++k) acc2 += msg[k] * W_upd[(HIDDEN + k) * HIDDEN + j];
    M2[p * HIDDEN + j] = acc2;

    if (p < NREL) {
        float acc3 = 0.f;
        #pragma unroll 8
        for (int i = 0; i < HIDDEN; ++i) acc3 += rel_emb[p * HIDDEN + i] * W_upd[i * HIDDEN + j];
        Hc[p * HIDDEN + j] = acc3;
    }
}

// ---------------------------------------------------------------------------
// Counting sort, phase 1: histogram of edge_ac. counts is L2-resident (4 MB).
// ---------------------------------------------------------------------------
__global__ void histogram(const int* __restrict__ edge_ac,
                          int* __restrict__ counts, int num_tri) {
    int i = blockIdx.x * blockDim.x + threadIdx.x;
    const int stride = gridDim.x * blockDim.x;
    for (; i < num_tri; i += stride) atomicAdd(&counts[edge_ac[i]], 1);
}

// Phase 2a: per-tile reduce (tile = 4096 counts) -> blocksums.
__global__ void scan_reduce(const int* __restrict__ counts,
                            int* __restrict__ blocksums, int n) {
    __shared__ int sdata[256];
    const int base = blockIdx.x * TILE;
    int s = 0;
    #pragma unroll
    for (int k = 0; k < 16; ++k) {
        const int i = base + k * 256 + threadIdx.x;   // coalesced
        if (i < n) s += counts[i];
    }
    sdata[threadIdx.x] = s;
    __syncthreads();
    for (int off = 128; off > 0; off >>= 1) {
        if (threadIdx.x < off) sdata[threadIdx.x] += sdata[threadIdx.x + off];
        __syncthreads();
    }
    if (threadIdx.x == 0) blocksums[blockIdx.x] = sdata[0];
}

// Phase 2b: exclusive scan of blocksums (single block; requires nb <= 256,
// i.e. n <= 1,048,576 — holds for NUM_EDGE = 1e6). Also writes offsets[n]=T.
__global__ void scan_blocksums(int* __restrict__ blocksums, int nb,
                               int* __restrict__ offsets, int num_edge, int num_tri) {
    __shared__ int sdata[256];
    const int v = (threadIdx.x < nb) ? blocksums[threadIdx.x] : 0;
    sdata[threadIdx.x] = v;
    __syncthreads();
    for (int off = 1; off < 256; off <<= 1) {
        const int t = (threadIdx.x >= off) ? sdata[threadIdx.x - off] : 0;
        __syncthreads();
        sdata[threadIdx.x] += t;
        __syncthreads();
    }
    if (threadIdx.x < nb) blocksums[threadIdx.x] = sdata[threadIdx.x] - v;  // exclusive
    if (threadIdx.x == 0) offsets[num_edge] = num_tri;
}

// Phase 2c: per-tile exclusive scan + add block base; writes offsets & cursor.
__global__ void scan_tile(const int* __restrict__ counts,
                          const int* __restrict__ blocksums,
                          int* __restrict__ offsets,
                          int* __restrict__ cursor, int n) {
    __shared__ int sdata[256];
    const int base = blockIdx.x * TILE + threadIdx.x * 16;
    int c[16];
    int s = 0;
    #pragma unroll
    for (int k = 0; k < 16; ++k) {
        const int i = base + k;
        c[k] = (i < n) ? counts[i] : 0;
        s += c[k];
    }
    sdata[threadIdx.x] = s;
    __syncthreads();
    for (int off = 1; off < 256; off <<= 1) {
        const int t = (threadIdx.x >= off) ? sdata[threadIdx.x - off] : 0;
        __syncthreads();
        sdata[threadIdx.x] += t;
        __syncthreads();
    }
    int run = blocksums[blockIdx.x] + (sdata[threadIdx.x] - s);  // exclusive prefix
    #pragma unroll
    for (int k = 0; k < 16; ++k) {
        const int i = base + k;
        if (i < n) {
            offsets[i] = run;
            cursor[i]  = run;
            run += c[k];
        }
    }
}

// Phase 3: scatter the 16-bit pair id into ac-sorted order (4 MB region).
__global__ void scatter_pairs(const int* __restrict__ rel,
                              const int* __restrict__ edge_ab,
                              const int* __restrict__ edge_bc,
                              const int* __restrict__ edge_ac,
                              int* __restrict__ cursor,
                              unsigned short* __restrict__ sorted_p, int num_tri) {
    int i = blockIdx.x * blockDim.x + threadIdx.x;
    const int stride = gridDim.x * blockDim.x;
    for (; i < num_tri; i += stride) {
        const int p = rel[edge_ab[i]] * NREL + rel[edge_bc[i]];
        const int pos = atomicAdd(&cursor[edge_ac[i]], 1);
        sorted_p[pos] = (unsigned short)p;
    }
}

// Phase 4: per-edge gather-accumulate + fused update. 16 lanes (float4 each)
// per edge row; 16 edges per 256-thread block; single coalesced out write.
__global__ void accumulate(const int* __restrict__ rel,
                           const int* __restrict__ offsets,
                           const unsigned short* __restrict__ sorted_p,
                           const float* __restrict__ M2,
                           const float* __restrict__ Hc,
                           float* __restrict__ out, int num_edge) {
    const int sub = threadIdx.x >> 4;   // 0..15: edge slot within block
    const int l   = threadIdx.x & 15;   // float4 lane within row
    int e = blockIdx.x * 16 + sub;
    const int estride = gridDim.x * 16;
    for (; e < num_edge; e += estride) {
        const int beg = offsets[e];
        const int end = offsets[e + 1];
        float4 acc = make_float4(0.f, 0.f, 0.f, 0.f);
        for (int k = beg; k < end; ++k) {
            const int p = sorted_p[k];                       // broadcast in subgroup
            const float4 m = ((const float4*)(M2 + p * HIDDEN))[l];
            acc.x += m.x; acc.y += m.y; acc.z += m.z; acc.w += m.w;
        }
        const float4 h = ((const float4*)(Hc + rel[e] * HIDDEN))[l];
        float4 o;
        o.x = fmaxf(acc.x + h.x, 0.f);
        o.y = fmaxf(acc.y + h.y, 0.f);
        o.z = fmaxf(acc.z + h.z, 0.f);
        o.w = fmaxf(acc.w + h.w, 0.f);
        ((float4*)out)[(size_t)e * 16 + l] = o;
    }
}

// --------------------------- fallback (round-1) path -----------------------
__global__ void scatter_tri(const int* __restrict__ rel,
                            const int* __restrict__ edge_ab,
                            const int* __restrict__ edge_bc,
                            const int* __restrict__ edge_ac,
                            const float* __restrict__ M2,
                            float* __restrict__ out, int num_tri) {
    const int lane   = threadIdx.x & 63;
    const int wave   = (int)((blockIdx.x * blockDim.x + threadIdx.x) >> 6);
    const int nwaves = (int)((gridDim.x * blockDim.x) >> 6);
    for (int t = wave; t < num_tri; t += nwaves) {
        const int p = rel[edge_ab[t]] * NREL + rel[edge_bc[t]];
        const float v = M2[p * HIDDEN + lane];
        unsafeAtomicAdd(&out[(size_t)edge_ac[t] * HIDDEN + lane], v);
    }
}

__global__ void finalize(const int* __restrict__ rel,
                         const float* __restrict__ Hc,
                         float* __restrict__ out, int num_edge) {
    const int total = num_edge * (HIDDEN / 4);
    int i = blockIdx.x * blockDim.x + threadIdx.x;
    const int stride = gridDim.x * blockDim.x;
    for (; i < total; i += stride) {
        const int e = i >> 4;
        const int q = i & 15;
        float4 a = ((const float4*)out)[i];
        float4 h = ((const float4*)(Hc + rel[e] * HIDDEN))[q];
        float4 o;
        o.x = fmaxf(a.x + h.x, 0.f);
        o.y = fmaxf(a.y + h.y, 0.f);
        o.z = fmaxf(a.z + h.z, 0.f);
        o.w = fmaxf(a.w + h.w, 0.f);
        ((float4*)out)[i] = o;
    }
}
// ---------------------------------------------------------------------------

extern "C" void kernel_launch(void* const* d_in, const int* in_sizes, int n_in,
                              void* d_out, int out_size, void* d_ws, size_t ws_size,
                              hipStream_t stream) {
    const float* rel_emb = (const float*)d_in[0];
    const float* W_msg   = (const float*)d_in[1];
    const float* W_upd   = (const float*)d_in[2];
    const int* rel     = (const int*)d_in[5];
    const int* edge_ab = (const int*)d_in[6];
    const int* edge_bc = (const int*)d_in[7];
    const int* edge_ac = (const int*)d_in[8];
    float* out = (float*)d_out;

    const int num_edge = in_sizes[5];
    const int num_tri  = in_sizes[6];
    const int nb = (num_edge + TILE - 1) / TILE;   // scan tiles (245 for 1e6)

    // ---- workspace layout (256B-aligned offsets) ----
    char* ws = (char*)d_ws;
    size_t off = 0;
    auto alloc = [&](size_t bytes) { char* p = ws + off; off = (off + bytes + 255) & ~(size_t)255; return p; };
    float*          M2        = (float*)alloc((size_t)NPAIR * HIDDEN * 4);   // 640 KB
    float*          Hc        = (float*)alloc((size_t)NREL * HIDDEN * 4);    // 12.8 KB
    int*            counts    = (int*)alloc((size_t)num_edge * 4);           // 4 MB
    int*            offsets   = (int*)alloc((size_t)(num_edge + 1) * 4);     // 4 MB
    int*            cursor    = (int*)alloc((size_t)num_edge * 4);           // 4 MB
    unsigned short* sorted_p  = (unsigned short*)alloc((size_t)num_tri * 2); // 4 MB
    int*            blocksums = (int*)alloc((size_t)nb * 4);
    const size_t required = off;

    precompute_tables<<<NPAIR, HIDDEN, 0, stream>>>(rel_emb, W_msg, W_upd, M2, Hc);

    if (ws_size >= required && nb <= 256) {
        // ---- counting-sort path ----
        hipMemsetAsync(counts, 0, (size_t)num_edge * 4, stream);
        histogram<<<1024, 256, 0, stream>>>(edge_ac, counts, num_tri);
        scan_reduce<<<nb, 256, 0, stream>>>(counts, blocksums, num_edge);
        scan_blocksums<<<1, 256, 0, stream>>>(blocksums, nb, offsets, num_edge, num_tri);
        scan_tile<<<nb, 256, 0, stream>>>(counts, blocksums, offsets, cursor, num_edge);
        scatter_pairs<<<2048, 256, 0, stream>>>(rel, edge_ab, edge_bc, edge_ac,
                                                cursor, sorted_p, num_tri);
        const int ablocks = (num_edge + 15) / 16;
        accumulate<<<ablocks, 256, 0, stream>>>(rel, offsets, sorted_p, M2, Hc, out, num_edge);
    } else {
        // ---- fallback: round-1 atomic path ----
        hipMemsetAsync(d_out, 0, (size_t)out_size * sizeof(float), stream);
        scatter_tri<<<8192, 256, 0, stream>>>(rel, edge_ab, edge_bc, edge_ac, M2, out, num_tri);
        const int total4 = num_edge * (HIDDEN / 4);
        int fin_blocks = (total4 + 255) / 256;
        if (fin_blocks > 65535 * 8) fin_blocks = 65535 * 8;
        finalize<<<fin_blocks, 256, 0, stream>>>(rel, Hc, out, num_edge);
    }
}

// Round 3
// 481.057 us; speedup vs baseline: 1.7080x; 1.1938x over previous
//
#include <hip/hip_runtime.h>

#define HIDDEN 64
#define NREL 50
#define NPAIR (NREL * NREL)
#define TILE 4096           // scan tile: 256 threads x 16 elements

// ---------------------------------------------------------------------------
// Kernel 1: precompute tables.
//   M2[p][j] = sum_k relu( sum_i pair_p[i] * W_msg[i][k] ) * W_upd[64+k][j]
//   Hc[r][j] = sum_i rel_emb[r][i] * W_upd[i][j]
// ---------------------------------------------------------------------------
__global__ void precompute_tables(const float* __restrict__ rel_emb,
                                  const float* __restrict__ W_msg,
                                  const float* __restrict__ W_upd,
                                  float* __restrict__ M2,
                                  float* __restrict__ Hc) {
    const int p = blockIdx.x;      // 0..2499
    const int j = threadIdx.x;     // 0..63
    const int ra = p / NREL, rb = p % NREL;

    __shared__ float msg[HIDDEN];

    const float* ha = rel_emb + ra * HIDDEN;
    const float* hb = rel_emb + rb * HIDDEN;

    float acc = 0.f;
    #pragma unroll 8
    for (int i = 0; i < HIDDEN; ++i) acc += ha[i] * W_msg[i * HIDDEN + j];
    #pragma unroll 8
    for (int i = 0; i < HIDDEN; ++i) acc += hb[i] * W_msg[(HIDDEN + i) * HIDDEN + j];
    msg[j] = fmaxf(acc, 0.f);
    __syncthreads();

    float acc2 = 0.f;
    #pragma unroll 8
    for (int k = 0; k < HIDDEN; ++k) acc2 += msg[k] * W_upd[(HIDDEN + k) * HIDDEN + j];
    M2[p * HIDDEN + j] = acc2;

    if (p < NREL) {
        float acc3 = 0.f;
        #pragma unroll 8
        for (int i = 0; i < HIDDEN; ++i) acc3 += rel_emb[p * HIDDEN + i] * W_upd[i * HIDDEN + j];
        Hc[p * HIDDEN + j] = acc3;
    }
}

// ---------------------------------------------------------------------------
// Kernel 2: histogram + rank/pair capture. The atomic's return value IS the
// triangle's unique slot within its edge bucket -> no second atomic pass.
// packed[i] = (rank << 16) | p   (rank < 2^16: max degree of random data ~15;
//                                 p < 2500)
// ---------------------------------------------------------------------------
__global__ void hist_capture(const int* __restrict__ rel,
                             const int* __restrict__ edge_ab,
                             const int* __restrict__ edge_bc,
                             const int* __restrict__ edge_ac,
                             int* __restrict__ counts,
                             unsigned int* __restrict__ packed, int num_tri) {
    int i = blockIdx.x * blockDim.x + threadIdx.x;
    const int stride = gridDim.x * blockDim.x;
    for (; i < num_tri; i += stride) {
        const int p = rel[edge_ab[i]] * NREL + rel[edge_bc[i]];
        const unsigned int r = (unsigned int)atomicAdd(&counts[edge_ac[i]], 1);
        packed[i] = (r << 16) | (unsigned int)p;
    }
}

// Phase 2a: per-tile reduce (tile = 4096 counts) -> blocksums.
__global__ void scan_reduce(const int* __restrict__ counts,
                            int* __restrict__ blocksums, int n) {
    __shared__ int sdata[256];
    const int base = blockIdx.x * TILE;
    int s = 0;
    #pragma unroll
    for (int k = 0; k < 16; ++k) {
        const int i = base + k * 256 + threadIdx.x;   // coalesced
        if (i < n) s += counts[i];
    }
    sdata[threadIdx.x] = s;
    __syncthreads();
    for (int off = 128; off > 0; off >>= 1) {
        if (threadIdx.x < off) sdata[threadIdx.x] += sdata[threadIdx.x + off];
        __syncthreads();
    }
    if (threadIdx.x == 0) blocksums[blockIdx.x] = sdata[0];
}

// Phase 2b: exclusive scan of blocksums (single block; nb <= 256).
__global__ void scan_blocksums(int* __restrict__ blocksums, int nb,
                               int* __restrict__ offsets, int num_edge, int num_tri) {
    __shared__ int sdata[256];
    const int v = (threadIdx.x < nb) ? blocksums[threadIdx.x] : 0;
    sdata[threadIdx.x] = v;
    __syncthreads();
    for (int off = 1; off < 256; off <<= 1) {
        const int t = (threadIdx.x >= off) ? sdata[threadIdx.x - off] : 0;
        __syncthreads();
        sdata[threadIdx.x] += t;
        __syncthreads();
    }
    if (threadIdx.x < nb) blocksums[threadIdx.x] = sdata[threadIdx.x] - v;  // exclusive
    if (threadIdx.x == 0) offsets[num_edge] = num_tri;
}

// Phase 2c: per-tile exclusive scan + block base -> offsets (no cursor copy).
__global__ void scan_tile(const int* __restrict__ counts,
                          const int* __restrict__ blocksums,
                          int* __restrict__ offsets, int n) {
    __shared__ int sdata[256];
    const int base = blockIdx.x * TILE + threadIdx.x * 16;
    int c[16];
    int s = 0;
    #pragma unroll
    for (int k = 0; k < 16; ++k) {
        const int i = base + k;
        c[k] = (i < n) ? counts[i] : 0;
        s += c[k];
    }
    sdata[threadIdx.x] = s;
    __syncthreads();
    for (int off = 1; off < 256; off <<= 1) {
        const int t = (threadIdx.x >= off) ? sdata[threadIdx.x - off] : 0;
        __syncthreads();
        sdata[threadIdx.x] += t;
        __syncthreads();
    }
    int run = blocksums[blockIdx.x] + (sdata[threadIdx.x] - s);  // exclusive prefix
    #pragma unroll
    for (int k = 0; k < 16; ++k) {
        const int i = base + k;
        if (i < n) { offsets[i] = run; run += c[k]; }
    }
}

// ---------------------------------------------------------------------------
// Kernel 3: placement. pos = offsets[ac] + rank. No atomics, no dependent
// chain beyond one gather.
// ---------------------------------------------------------------------------
__global__ void place(const int* __restrict__ edge_ac,
                      const unsigned int* __restrict__ packed,
                      const int* __restrict__ offsets,
                      unsigned short* __restrict__ sorted_p, int num_tri) {
    int i = blockIdx.x * blockDim.x + threadIdx.x;
    const int stride = gridDim.x * blockDim.x;
    for (; i < num_tri; i += stride) {
        const unsigned int v = packed[i];
        const int pos = offsets[edge_ac[i]] + (int)(v >> 16);
        sorted_p[pos] = (unsigned short)(v & 0xFFFFu);
    }
}

// ---------------------------------------------------------------------------
// Kernel 4: per-edge gather-accumulate + fused update, 2-way ILP.
// 16 lanes (float4 each) per edge row; 16 edges per 256-thread block.
// ---------------------------------------------------------------------------
__global__ void accumulate(const int* __restrict__ rel,
                           const int* __restrict__ offsets,
                           const unsigned short* __restrict__ sorted_p,
                           const float* __restrict__ M2,
                           const float* __restrict__ Hc,
                           float* __restrict__ out, int num_edge) {
    const int sub = threadIdx.x >> 4;   // 0..15: edge slot within block
    const int l   = threadIdx.x & 15;   // float4 lane within row
    int e = blockIdx.x * 16 + sub;
    const int estride = gridDim.x * 16;
    for (; e < num_edge; e += estride) {
        // independent loads first: row offsets, relation, bias row
        int k = offsets[e];
        const int end = offsets[e + 1];
        const int r = rel[e];
        const float4 h = ((const float4*)(Hc + r * HIDDEN))[l];

        float4 a0 = make_float4(0.f, 0.f, 0.f, 0.f);
        float4 a1 = make_float4(0.f, 0.f, 0.f, 0.f);
        for (; k + 2 <= end; k += 2) {
            const int p0 = sorted_p[k];
            const int p1 = sorted_p[k + 1];
            const float4 m0 = ((const float4*)M2)[p0 * 16 + l];
            const float4 m1 = ((const float4*)M2)[p1 * 16 + l];
            a0.x += m0.x; a0.y += m0.y; a0.z += m0.z; a0.w += m0.w;
            a1.x += m1.x; a1.y += m1.y; a1.z += m1.z; a1.w += m1.w;
        }
        if (k < end) {
            const int p0 = sorted_p[k];
            const float4 m0 = ((const float4*)M2)[p0 * 16 + l];
            a0.x += m0.x; a0.y += m0.y; a0.z += m0.z; a0.w += m0.w;
        }
        float4 o;
        o.x = fmaxf(a0.x + a1.x + h.x, 0.f);
        o.y = fmaxf(a0.y + a1.y + h.y, 0.f);
        o.z = fmaxf(a0.z + a1.z + h.z, 0.f);
        o.w = fmaxf(a0.w + a1.w + h.w, 0.f);
        ((float4*)out)[(size_t)e * 16 + l] = o;
    }
}

// --------------------------- fallback (round-1) path -----------------------
__global__ void scatter_tri(const int* __restrict__ rel,
                            const int* __restrict__ edge_ab,
                            const int* __restrict__ edge_bc,
                            const int* __restrict__ edge_ac,
                            const float* __restrict__ M2,
                            float* __restrict__ out, int num_tri) {
    const int lane   = threadIdx.x & 63;
    const int wave   = (int)((blockIdx.x * blockDim.x + threadIdx.x) >> 6);
    const int nwaves = (int)((gridDim.x * blockDim.x) >> 6);
    for (int t = wave; t < num_tri; t += nwaves) {
        const int p = rel[edge_ab[t]] * NREL + rel[edge_bc[t]];
        const float v = M2[p * HIDDEN + lane];
        unsafeAtomicAdd(&out[(size_t)edge_ac[t] * HIDDEN + lane], v);
    }
}

__global__ void finalize(const int* __restrict__ rel,
                         const float* __restrict__ Hc,
                         float* __restrict__ out, int num_edge) {
    const int total = num_edge * (HIDDEN / 4);
    int i = blockIdx.x * blockDim.x + threadIdx.x;
    const int stride = gridDim.x * blockDim.x;
    for (; i < total; i += stride) {
        const int e = i >> 4;
        const int q = i & 15;
        float4 a = ((const float4*)out)[i];
        float4 h = ((const float4*)(Hc + rel[e] * HIDDEN))[q];
        float4 o;
        o.x = fmaxf(a.x + h.x, 0.f);
        o.y = fmaxf(a.y + h.y, 0.f);
        o.z = fmaxf(a.z + h.z, 0.f);
        o.w = fmaxf(a.w + h.w, 0.f);
        ((float4*)out)[i] = o;
    }
}
// ---------------------------------------------------------------------------

extern "C" void kernel_launch(void* const* d_in, const int* in_sizes, int n_in,
                              void* d_out, int out_size, void* d_ws, size_t ws_size,
                              hipStream_t stream) {
    const float* rel_emb = (const float*)d_in[0];
    const float* W_msg   = (const float*)d_in[1];
    const float* W_upd   = (const float*)d_in[2];
    const int* rel     = (const int*)d_in[5];
    const int* edge_ab = (const int*)d_in[6];
    const int* edge_bc = (const int*)d_in[7];
    const int* edge_ac = (const int*)d_in[8];
    float* out = (float*)d_out;

    const int num_edge = in_sizes[5];
    const int num_tri  = in_sizes[6];
    const int nb = (num_edge + TILE - 1) / TILE;   // scan tiles (245 for 1e6)

    // ---- workspace layout (256B-aligned offsets) ----
    char* ws = (char*)d_ws;
    size_t off = 0;
    auto alloc = [&](size_t bytes) { char* p = ws + off; off = (off + bytes + 255) & ~(size_t)255; return p; };
    float*          M2        = (float*)alloc((size_t)NPAIR * HIDDEN * 4);   // 640 KB
    float*          Hc        = (float*)alloc((size_t)NREL * HIDDEN * 4);    // 12.8 KB
    int*            counts    = (int*)alloc((size_t)num_edge * 4);           // 4 MB
    int*            offsets   = (int*)alloc((size_t)(num_edge + 1) * 4);     // 4 MB
    unsigned int*   packed    = (unsigned int*)alloc((size_t)num_tri * 4);   // 8 MB
    unsigned short* sorted_p  = (unsigned short*)alloc((size_t)num_tri * 2); // 4 MB
    int*            blocksums = (int*)alloc((size_t)nb * 4);
    const size_t required = off;

    precompute_tables<<<NPAIR, HIDDEN, 0, stream>>>(rel_emb, W_msg, W_upd, M2, Hc);

    if (ws_size >= required && nb <= 256) {
        // ---- counting-sort path (no cursor, single atomic pass) ----
        hipMemsetAsync(counts, 0, (size_t)num_edge * 4, stream);
        hist_capture<<<2048, 256, 0, stream>>>(rel, edge_ab, edge_bc, edge_ac,
                                               counts, packed, num_tri);
        scan_reduce<<<nb, 256, 0, stream>>>(counts, blocksums, num_edge);
        scan_blocksums<<<1, 256, 0, stream>>>(blocksums, nb, offsets, num_edge, num_tri);
        scan_tile<<<nb, 256, 0, stream>>>(counts, blocksums, offsets, num_edge);
        place<<<2048, 256, 0, stream>>>(edge_ac, packed, offsets, sorted_p, num_tri);
        const int ablocks = (num_edge + 15) / 16;
        accumulate<<<ablocks, 256, 0, stream>>>(rel, offsets, sorted_p, M2, Hc, out, num_edge);
    } else {
        // ---- fallback: round-1 atomic path ----
        hipMemsetAsync(d_out, 0, (size_t)out_size * sizeof(float), stream);
        scatter_tri<<<8192, 256, 0, stream>>>(rel, edge_ab, edge_bc, edge_ac, M2, out, num_tri);
        const int total4 = num_edge * (HIDDEN / 4);
        int fin_blocks = (total4 + 255) / 256;
        if (fin_blocks > 65535 * 8) fin_blocks = 65535 * 8;
        finalize<<<fin_blocks, 256, 0, stream>>>(rel, Hc, out, num_edge);
    }
}